// Round 1
// baseline (975.917 us; speedup 1.0000x reference)
//
#include <hip/hip_runtime.h>
#include <hip/hip_bf16.h>

#define T_DIM 512
#define B_DIM 16
#define D_DIM 1024
#define N_DIM 512

typedef short s16x8 __attribute__((ext_vector_type(8)));
typedef float f32x4 __attribute__((ext_vector_type(4)));

__device__ __forceinline__ unsigned short f2bf(float f) {
    unsigned u = __float_as_uint(f);
    unsigned r = (u + 0x7fffu + ((u >> 16) & 1u)) >> 16;
    return (unsigned short)r;
}

__device__ __forceinline__ float fast_tanh(float x) {
    // tanh(x) = 1 - 2/(exp(2x)+1); v_exp_f32 computes 2^x
    float e = __builtin_amdgcn_exp2f(x * 2.885390082f); // 2*log2(e)
    return 1.0f - 2.0f * __builtin_amdgcn_rcpf(e + 1.0f);
}

// ---------------- projection GEMM: C[m,n] = sum_d x[m,d] * W[n,d] ----------
// M=8192 (t*B+b), K=1024, N=512. grid(128, 8, 3), block 256.
__global__ __launch_bounds__(256) void proj_gemm(
    const float* __restrict__ x,
    const float* __restrict__ Wk,
    const float* __restrict__ Wv,
    const float* __restrict__ Wq,
    float* __restrict__ kbuf, float* __restrict__ vbuf, float* __restrict__ qbuf)
{
    const float* W = (blockIdx.z == 0) ? Wk : (blockIdx.z == 1) ? Wv : Wq;
    float* out = (blockIdx.z == 0) ? kbuf : (blockIdx.z == 1) ? vbuf : qbuf;

    // padded stride 40 elems (80 B) -> frag ds_read_b128 lands 2-way (free)
    __shared__ __align__(16) unsigned short As[64 * 40];
    __shared__ __align__(16) unsigned short Bs[64 * 40];

    const int tid  = threadIdx.x;
    const int m0   = blockIdx.x * 64;
    const int n0   = blockIdx.y * 64;
    const int wave = tid >> 6;
    const int lane = tid & 63;
    const int l15  = lane & 15;
    const int quad = lane >> 4;

    const int srow = tid >> 2;       // 0..63
    const int scol = (tid & 3) * 8;  // 0,8,16,24

    f32x4 acc[4];
#pragma unroll
    for (int i = 0; i < 4; ++i) acc[i] = (f32x4)0.0f;

    for (int k0 = 0; k0 < D_DIM; k0 += 32) {
        __syncthreads();
        {
            const float* srcA = &x[(size_t)(m0 + srow) * D_DIM + k0 + scol];
            float4 a0 = *(const float4*)srcA;
            float4 a1 = *(const float4*)(srcA + 4);
            uint4 pa;
            pa.x = (unsigned)f2bf(a0.x) | ((unsigned)f2bf(a0.y) << 16);
            pa.y = (unsigned)f2bf(a0.z) | ((unsigned)f2bf(a0.w) << 16);
            pa.z = (unsigned)f2bf(a1.x) | ((unsigned)f2bf(a1.y) << 16);
            pa.w = (unsigned)f2bf(a1.z) | ((unsigned)f2bf(a1.w) << 16);
            *(uint4*)&As[srow * 40 + scol] = pa;

            const float* srcB = &W[(size_t)(n0 + srow) * D_DIM + k0 + scol];
            float4 b0 = *(const float4*)srcB;
            float4 b1 = *(const float4*)(srcB + 4);
            uint4 pb;
            pb.x = (unsigned)f2bf(b0.x) | ((unsigned)f2bf(b0.y) << 16);
            pb.y = (unsigned)f2bf(b0.z) | ((unsigned)f2bf(b0.w) << 16);
            pb.z = (unsigned)f2bf(b1.x) | ((unsigned)f2bf(b1.y) << 16);
            pb.w = (unsigned)f2bf(b1.z) | ((unsigned)f2bf(b1.w) << 16);
            *(uint4*)&Bs[srow * 40 + scol] = pb;
        }
        __syncthreads();
        // A-frag: A[m=lane&15][k=quad*8+j]; B-frag: B[k][n=lane&15] (= W[n][k])
        s16x8 af = *(const s16x8*)&As[(wave * 16 + l15) * 40 + quad * 8];
#pragma unroll
        for (int nt = 0; nt < 4; ++nt) {
            s16x8 bf = *(const s16x8*)&Bs[(nt * 16 + l15) * 40 + quad * 8];
            acc[nt] = __builtin_amdgcn_mfma_f32_16x16x32_bf16(af, bf, acc[nt], 0, 0, 0);
        }
    }
    // epilogue: D row = quad*4+reg (M), col = lane&15 (N)
#pragma unroll
    for (int nt = 0; nt < 4; ++nt) {
#pragma unroll
        for (int rg = 0; rg < 4; ++rg) {
            int row = m0 + wave * 16 + quad * 4 + rg;
            int col = n0 + nt * 16 + l15;
            out[(size_t)row * N_DIM + col] = acc[nt][rg];
        }
    }
}

// ---------------- k row-normalization (in place) ---------------------------
// one wave per (t,b) row; grid 2048, block 256
__global__ __launch_bounds__(256) void knorm(float* __restrict__ kbuf)
{
    const int wave = threadIdx.x >> 6;
    const int lane = threadIdx.x & 63;
    const int row  = blockIdx.x * 4 + wave;
    float* p = &kbuf[(size_t)row * N_DIM + lane * 8];
    float4 a = *(const float4*)p;
    float4 b = *(const float4*)(p + 4);
    float s = a.x*a.x + a.y*a.y + a.z*a.z + a.w*a.w
            + b.x*b.x + b.y*b.y + b.z*b.z + b.w*b.w;
#pragma unroll
    for (int m = 1; m < 64; m <<= 1) s += __shfl_xor(s, m, 64);
    float inv = 1.0f / (sqrtf(s) + 1e-6f);
    a.x *= inv; a.y *= inv; a.z *= inv; a.w *= inv;
    b.x *= inv; b.y *= inv; b.z *= inv; b.w *= inv;
    *(float4*)p = a;
    *(float4*)(p + 4) = b;
}

// ---------------- sequential scan ------------------------------------------
// grid(32, 16): x = row-chunk (16 rows), y = batch. block 256.
// thread (r=tid>>4, tj=tid&15) owns S[b][chunk*16+r][tj*32 .. tj*32+31] in regs.
__global__ __launch_bounds__(256) void scan_kernel(
    const float* __restrict__ kbuf, const float* __restrict__ vbuf,
    const float* __restrict__ qbuf, float* __restrict__ out)
{
    // k at [0..576), q at [576..1152); per-chunk stride 36 floats (144 B)
    __shared__ __align__(16) float kq[2 * 576];

    const int tid = threadIdx.x;
    const int r   = tid >> 4;
    const int tj  = tid & 15;
    const int b   = blockIdx.y;
    const int i   = blockIdx.x * 16 + r;

    float S[32];
#pragma unroll
    for (int u = 0; u < 32; ++u) S[u] = 0.0f;

    const int j2   = 2 * tid;                 // element this thread stages
    const int ldsw = r * 36 + 2 * tj;         // (j2>>5)*36 + (j2&31)
    const int ldsr = tj * 36;

    for (int t = 0; t < T_DIM; ++t) {
        const size_t ofs = ((size_t)t * B_DIM + b) * N_DIM;
        __syncthreads();
        {
            float2 kv = *(const float2*)&kbuf[ofs + j2];
            float2 qv = *(const float2*)&qbuf[ofs + j2];
            kq[ldsw]           = kv.x;
            kq[ldsw + 1]       = kv.y;
            kq[576 + ldsw]     = qv.x;
            kq[576 + ldsw + 1] = qv.y;
        }
        __syncthreads();

        float4 kf[8], qf[8];
#pragma unroll
        for (int u = 0; u < 8; ++u) {
            kf[u] = *(const float4*)&kq[ldsr + 4 * u];
            qf[u] = *(const float4*)&kq[576 + ldsr + 4 * u];
        }

        // retrieved_i = sum_j S_ij * k_j
        float racc = 0.f;
#pragma unroll
        for (int u = 0; u < 8; ++u)
            racc += S[4*u]   * kf[u].x + S[4*u+1] * kf[u].y
                  + S[4*u+2] * kf[u].z + S[4*u+3] * kf[u].w;
#pragma unroll
        for (int m = 1; m < 16; m <<= 1) racc += __shfl_xor(racc, m, 64);

        const float delta = vbuf[ofs + i] - racc;

        // S_ij = tanh(S_ij + delta_i * k_j);  sq += S_ij * q_j
        float sq = 0.f;
#pragma unroll
        for (int u = 0; u < 8; ++u) {
            float s0 = fast_tanh(S[4*u]   + delta * kf[u].x); S[4*u]   = s0; sq += s0 * qf[u].x;
            float s1 = fast_tanh(S[4*u+1] + delta * kf[u].y); S[4*u+1] = s1; sq += s1 * qf[u].y;
            float s2 = fast_tanh(S[4*u+2] + delta * kf[u].z); S[4*u+2] = s2; sq += s2 * qf[u].z;
            float s3 = fast_tanh(S[4*u+3] + delta * kf[u].w); S[4*u+3] = s3; sq += s3 * qf[u].w;
        }
#pragma unroll
        for (int m = 1; m < 16; m <<= 1) sq += __shfl_xor(sq, m, 64);

        if (tj == 0) {
            // out = Sq * silu(Sq) = Sq^2 * sigmoid(Sq)
            float sg = __builtin_amdgcn_rcpf(
                1.0f + __builtin_amdgcn_exp2f(-sq * 1.44269504f));
            out[ofs + i] = sq * sq * sg;
        }
    }

    // S_final -> d_out[T*B*N + b*N*N + i*N + j]
    const size_t so = (size_t)T_DIM * B_DIM * N_DIM
                    + ((size_t)b * N_DIM + i) * N_DIM + (size_t)tj * 32;
#pragma unroll
    for (int u = 0; u < 8; ++u) {
        float4 v4;
        v4.x = S[4*u]; v4.y = S[4*u+1]; v4.z = S[4*u+2]; v4.w = S[4*u+3];
        *(float4*)&out[so + 4 * u] = v4;
    }
}

extern "C" void kernel_launch(void* const* d_in, const int* in_sizes, int n_in,
                              void* d_out, int out_size, void* d_ws, size_t ws_size,
                              hipStream_t stream) {
    const float* x  = (const float*)d_in[0];
    const float* Wk = (const float*)d_in[1];
    const float* Wv = (const float*)d_in[2];
    const float* Wq = (const float*)d_in[3];
    float* outp = (float*)d_out;

    const size_t MN = (size_t)T_DIM * B_DIM * N_DIM; // 8192*512
    float* kbuf = (float*)d_ws;
    float* vbuf = kbuf + MN;
    float* qbuf = vbuf + MN;

    proj_gemm<<<dim3(128, 8, 3), 256, 0, stream>>>(x, Wk, Wv, Wq, kbuf, vbuf, qbuf);
    knorm<<<2048, 256, 0, stream>>>(kbuf);
    scan_kernel<<<dim3(32, 16), 256, 0, stream>>>(kbuf, vbuf, qbuf, outp);
}